// Round 1
// baseline (781.626 us; speedup 1.0000x reference)
//
#include <hip/hip_runtime.h>

#define N_NODES 10000
#define N_EDGES 320000
#define N_PAIRS 1000000

// ---------------- CSR build ----------------
__global__ __launch_bounds__(256) void k_zero_cnt(int* cnt) {
    int i = blockIdx.x * 256 + threadIdx.x;
    if (i < N_NODES) cnt[i] = 0;
}

__global__ __launch_bounds__(256) void k_hist(const int* __restrict__ ei, int* __restrict__ cnt) {
    int e = blockIdx.x * 256 + threadIdx.x;
    if (e < N_EDGES) atomicAdd(&cnt[ei[N_EDGES + e]], 1);
}

__global__ __launch_bounds__(1024) void k_scan(const int* __restrict__ cnt,
                                               int* __restrict__ off, int* __restrict__ cursor) {
    __shared__ int part[1024];
    int t = threadIdx.x;
    int base = t * 10;
    int s = 0;
#pragma unroll
    for (int i = 0; i < 10; i++) {
        int idx = base + i;
        if (idx < N_NODES) s += cnt[idx];
    }
    part[t] = s;
    __syncthreads();
    for (int d = 1; d < 1024; d <<= 1) {
        int v = (t >= d) ? part[t - d] : 0;
        __syncthreads();
        part[t] += v;
        __syncthreads();
    }
    int run = (t == 0) ? 0 : part[t - 1];
#pragma unroll
    for (int i = 0; i < 10; i++) {
        int idx = base + i;
        if (idx < N_NODES) {
            off[idx] = run;
            cursor[idx] = run;
            run += cnt[idx];
        }
    }
    if (t == 0) off[N_NODES] = N_EDGES;
}

__global__ __launch_bounds__(256) void k_scatter(const int* __restrict__ ei, const float* __restrict__ ew,
                                                 int* __restrict__ cursor,
                                                 int* __restrict__ csr_src, float* __restrict__ csr_ew) {
    int e = blockIdx.x * 256 + threadIdx.x;
    if (e < N_EDGES) {
        int d = ei[N_EDGES + e];
        int pos = atomicAdd(&cursor[d], 1);
        csr_src[pos] = ei[e];
        csr_ew[pos] = ew[e];
    }
}

// ---------------- aggregation: wave per node ----------------
template <int C>
__global__ __launch_bounds__(256) void k_agg(const float* __restrict__ h, const int* __restrict__ off,
                                             const int* __restrict__ csr_src, const float* __restrict__ csr_ew,
                                             float* __restrict__ agg) {
    int wave = (blockIdx.x * 256 + threadIdx.x) >> 6;
    int lane = threadIdx.x & 63;
    if (wave >= N_NODES) return;
    int beg = off[wave], end = off[wave + 1];
    if constexpr (C == 256) {
        int col = lane * 4;
        float4 acc = {0.f, 0.f, 0.f, 0.f};
        for (int e = beg; e < end; e++) {
            int s = csr_src[e];
            float w = csr_ew[e];
            float4 v = *(const float4*)&h[s * 256 + col];
            acc.x += w * v.x; acc.y += w * v.y; acc.z += w * v.z; acc.w += w * v.w;
        }
        *(float4*)&agg[wave * 256 + col] = acc;
    } else {
        int col = lane * 2;
        float2 acc = {0.f, 0.f};
        for (int e = beg; e < end; e++) {
            int s = csr_src[e];
            float w = csr_ew[e];
            float2 v = *(const float2*)&h[s * 128 + col];
            acc.x += w * v.x; acc.y += w * v.y;
        }
        *(float2*)&agg[wave * 128 + col] = acc;
    }
}

// ---------------- fused dual-GEMM: out = act(A1@W1 [+ A2@W2] [+ bias]) ----------------
// W row-major [K x NC]. BM=64 BN=64 BK=16, 256 threads, 4x4 micro-tile.
template <bool RELU>
__global__ __launch_bounds__(256) void k_gemm(const float* __restrict__ A1, const float* __restrict__ W1,
                                              const float* __restrict__ A2, const float* __restrict__ W2,
                                              const float* __restrict__ bias,
                                              float* __restrict__ out, int M, int K, int NC) {
    const int BM = 64, BN = 64, BK = 16;
    __shared__ float As[BM][BK + 1];
    __shared__ float Bs[BK][BN];
    int tid = threadIdx.x;
    int tx = tid & 15, ty = tid >> 4;
    int row0 = blockIdx.x * BM, col0 = blockIdx.y * BN;
    float acc[4][4] = {};
    int npass = A2 ? 2 : 1;
    for (int pass = 0; pass < npass; ++pass) {
        const float* Ap = pass ? A2 : A1;
        const float* Wp = pass ? W2 : W1;
        for (int kk = 0; kk < K; kk += BK) {
#pragma unroll
            for (int i = tid; i < BM * BK; i += 256) {
                int m = i >> 4, k = i & 15;
                int r = row0 + m;
                As[m][k] = (r < M) ? Ap[r * K + kk + k] : 0.f;
            }
#pragma unroll
            for (int i = tid; i < BK * BN; i += 256) {
                int k = i >> 6, j = i & 63;
                Bs[k][j] = Wp[(kk + k) * NC + col0 + j];
            }
            __syncthreads();
#pragma unroll
            for (int k = 0; k < BK; k++) {
                float a[4], b[4];
#pragma unroll
                for (int r = 0; r < 4; r++) a[r] = As[ty * 4 + r][k];
#pragma unroll
                for (int c = 0; c < 4; c++) b[c] = Bs[k][tx * 4 + c];
#pragma unroll
                for (int r = 0; r < 4; r++)
#pragma unroll
                    for (int c = 0; c < 4; c++) acc[r][c] += a[r] * b[c];
            }
            __syncthreads();
        }
    }
#pragma unroll
    for (int r = 0; r < 4; r++) {
        int rr = row0 + ty * 4 + r;
        if (rr >= M) continue;
#pragma unroll
        for (int c = 0; c < 4; c++) {
            int cc = col0 + tx * 4 + c;
            float v = acc[r][c] + (bias ? bias[cc] : 0.f);
            if (RELU) v = fmaxf(v, 0.f);
            out[rr * NC + cc] = v;
        }
    }
}

// ---------------- decoder: wave per pair ----------------
__global__ __launch_bounds__(256) void k_decoder(const float* __restrict__ Ab, const float* __restrict__ Bb,
                                                 const int* __restrict__ el, const float* __restrict__ bd1,
                                                 const float* __restrict__ Wd2, const float* __restrict__ bd2,
                                                 float* __restrict__ out) {
    int lane = threadIdx.x & 63;
    int wave = (blockIdx.x * 256 + threadIdx.x) >> 6;
    int nwaves = (gridDim.x * 256) >> 6;
    int col = lane * 4;
    const float4 b1 = *(const float4*)&bd1[col];
    const float4 w2 = *(const float4*)&Wd2[col];
    const float b2 = bd2[0];
    for (int p = wave; p < N_PAIRS; p += nwaves) {
        int s = el[p], d = el[N_PAIRS + p];
        float4 a = *(const float4*)&Ab[s * 256 + col];
        float4 b = *(const float4*)&Bb[d * 256 + col];
        float h0 = fmaxf(a.x + b.x + b1.x, 0.f);
        float h1 = fmaxf(a.y + b.y + b1.y, 0.f);
        float h2 = fmaxf(a.z + b.z + b1.z, 0.f);
        float h3 = fmaxf(a.w + b.w + b1.w, 0.f);
        float r = h0 * w2.x + h1 * w2.y + h2 * w2.z + h3 * w2.w;
#pragma unroll
        for (int off = 32; off; off >>= 1) r += __shfl_down(r, off, 64);
        if (lane == 0) out[p] = r + b2;
    }
}

extern "C" void kernel_launch(void* const* d_in, const int* in_sizes, int n_in,
                              void* d_out, int out_size, void* d_ws, size_t ws_size,
                              hipStream_t stream) {
    const float* x   = (const float*)d_in[0];
    const int*   ei  = (const int*)d_in[1];
    const float* ew  = (const float*)d_in[2];
    const int*   el  = (const int*)d_in[3];
    const float* Wr1 = (const float*)d_in[4];
    const float* br1 = (const float*)d_in[5];
    const float* Wo1 = (const float*)d_in[6];
    const float* Wr2 = (const float*)d_in[7];
    const float* br2 = (const float*)d_in[8];
    const float* Wo2 = (const float*)d_in[9];
    const float* Wr3 = (const float*)d_in[10];
    const float* br3 = (const float*)d_in[11];
    const float* Wo3 = (const float*)d_in[12];
    const float* Wd1 = (const float*)d_in[13];
    const float* bd1 = (const float*)d_in[14];
    const float* Wd2 = (const float*)d_in[15];
    const float* bd2 = (const float*)d_in[16];
    float* out = (float*)d_out;

    char* ws = (char*)d_ws;
    size_t o = 0;
    auto alloc = [&](size_t bytes) { size_t p = o; o += (bytes + 255) & ~(size_t)255; return p; };
    int*   cnt     = (int*)(ws + alloc(N_NODES * 4));
    int*   cursor  = (int*)(ws + alloc(N_NODES * 4));
    int*   off     = (int*)(ws + alloc((N_NODES + 1) * 4));
    int*   csr_src = (int*)(ws + alloc(N_EDGES * 4));
    float* csr_ew  = (float*)(ws + alloc(N_EDGES * 4));
    float* agg     = (float*)(ws + alloc((size_t)N_NODES * 256 * 4));  // reused as Bbuf
    float* h1      = (float*)(ws + alloc((size_t)N_NODES * 256 * 4));  // reused as Abuf
    float* h2      = (float*)(ws + alloc((size_t)N_NODES * 128 * 4));
    float* z       = (float*)(ws + alloc((size_t)N_NODES * 128 * 4));
    float* Abuf = h1;
    float* Bbuf = agg;

    // CSR build
    k_zero_cnt<<<(N_NODES + 255) / 256, 256, 0, stream>>>(cnt);
    k_hist<<<(N_EDGES + 255) / 256, 256, 0, stream>>>(ei, cnt);
    k_scan<<<1, 1024, 0, stream>>>(cnt, off, cursor);
    k_scatter<<<(N_EDGES + 255) / 256, 256, 0, stream>>>(ei, ew, cursor, csr_src, csr_ew);

    const int AGG_BLOCKS = (N_NODES + 3) / 4;  // 4 waves/block
    // Layer 1: in x (256) -> h1 (256), relu
    k_agg<256><<<AGG_BLOCKS, 256, 0, stream>>>(x, off, csr_src, csr_ew, agg);
    {
        dim3 g((N_NODES + 63) / 64, 256 / 64);
        k_gemm<true><<<g, 256, 0, stream>>>(agg, Wr1, x, Wo1, br1, h1, N_NODES, 256, 256);
    }
    // Layer 2: h1 (256) -> h2 (128), relu
    k_agg<256><<<AGG_BLOCKS, 256, 0, stream>>>(h1, off, csr_src, csr_ew, agg);
    {
        dim3 g((N_NODES + 63) / 64, 128 / 64);
        k_gemm<true><<<g, 256, 0, stream>>>(agg, Wr2, h1, Wo2, br2, h2, N_NODES, 256, 128);
    }
    // Layer 3: h2 (128) -> z (128), no relu
    k_agg<128><<<AGG_BLOCKS, 256, 0, stream>>>(h2, off, csr_src, csr_ew, agg);
    {
        dim3 g((N_NODES + 63) / 64, 128 / 64);
        k_gemm<false><<<g, 256, 0, stream>>>(agg, Wr3, h2, Wo3, br3, z, N_NODES, 128, 128);
    }
    // Decoder precompute: A = z @ Wd1[:128,:], B = z @ Wd1[128:,:]
    {
        dim3 g((N_NODES + 63) / 64, 256 / 64);
        k_gemm<false><<<g, 256, 0, stream>>>(z, Wd1, nullptr, nullptr, nullptr, Abuf, N_NODES, 128, 256);
        k_gemm<false><<<g, 256, 0, stream>>>(z, Wd1 + 128 * 256, nullptr, nullptr, nullptr, Bbuf, N_NODES, 128, 256);
    }
    // Decoder: wave per pair
    k_decoder<<<1024, 256, 0, stream>>>(Abuf, Bbuf, el, bd1, Wd2, bd2, out);
}

// Round 2
// 511.719 us; speedup vs baseline: 1.5274x; 1.5274x over previous
//
#include <hip/hip_runtime.h>

#define N_NODES 10000
#define N_EDGES 320000
#define N_PAIRS 1000000

typedef unsigned short ushort_t;

__device__ inline float blo(unsigned int u) { return __uint_as_float(u << 16); }
__device__ inline float bhi(unsigned int u) { return __uint_as_float(u & 0xffff0000u); }
__device__ inline ushort_t f2bf(float f) {
    unsigned int u = __float_as_uint(f);
    unsigned int r = (u + 0x7fffu + ((u >> 16) & 1u)) >> 16;
    return (ushort_t)r;
}
__device__ inline void stout(float* p, float v) { *p = v; }
__device__ inline void stout(ushort_t* p, float v) { *p = f2bf(v); }

// ---------------- CSR build ----------------
__global__ __launch_bounds__(256) void k_zero_cnt(int* cnt) {
    int i = blockIdx.x * 256 + threadIdx.x;
    if (i < N_NODES) cnt[i] = 0;
}

__global__ __launch_bounds__(256) void k_hist(const int* __restrict__ ei, int* __restrict__ cnt) {
    int e = blockIdx.x * 256 + threadIdx.x;
    if (e < N_EDGES) atomicAdd(&cnt[ei[N_EDGES + e]], 1);
}

__global__ __launch_bounds__(1024) void k_scan(const int* __restrict__ cnt,
                                               int* __restrict__ off, int* __restrict__ cursor) {
    __shared__ int part[1024];
    int t = threadIdx.x;
    int base = t * 10;
    int s = 0;
#pragma unroll
    for (int i = 0; i < 10; i++) {
        int idx = base + i;
        if (idx < N_NODES) s += cnt[idx];
    }
    part[t] = s;
    __syncthreads();
    for (int d = 1; d < 1024; d <<= 1) {
        int v = (t >= d) ? part[t - d] : 0;
        __syncthreads();
        part[t] += v;
        __syncthreads();
    }
    int run = (t == 0) ? 0 : part[t - 1];
#pragma unroll
    for (int i = 0; i < 10; i++) {
        int idx = base + i;
        if (idx < N_NODES) {
            off[idx] = run;
            cursor[idx] = run;
            run += cnt[idx];
        }
    }
    if (t == 0) off[N_NODES] = N_EDGES;
}

__global__ __launch_bounds__(256) void k_scatter(const int* __restrict__ ei, const float* __restrict__ ew,
                                                 int* __restrict__ cursor,
                                                 int* __restrict__ csr_src, float* __restrict__ csr_ew) {
    int e = blockIdx.x * 256 + threadIdx.x;
    if (e < N_EDGES) {
        int d = ei[N_EDGES + e];
        int pos = atomicAdd(&cursor[d], 1);
        csr_src[pos] = ei[e];
        csr_ew[pos] = ew[e];
    }
}

// ---------------- fused agg epilogue: hout = act(agg(P) + R + bias) ----------------
// P is bf16 [N, C] (gathered), R fp32 [N, C], hout fp32 [N, C]. Wave per node.
template <int C, bool RELU>
__global__ __launch_bounds__(256) void k_aggf(const ushort_t* __restrict__ P, const float* __restrict__ R,
                                              const float* __restrict__ bias,
                                              const int* __restrict__ off, const int* __restrict__ csr_src,
                                              const float* __restrict__ csr_ew,
                                              float* __restrict__ hout) {
    int wave = (blockIdx.x * 256 + threadIdx.x) >> 6;
    int lane = threadIdx.x & 63;
    if (wave >= N_NODES) return;
    int beg = off[wave], end = off[wave + 1];
    if constexpr (C == 256) {
        int col = lane * 4;
        float4 acc = {0.f, 0.f, 0.f, 0.f};
        for (int e = beg; e < end; e++) {
            int s = csr_src[e];
            float w = csr_ew[e];
            uint2 u = *(const uint2*)&P[(size_t)s * 256 + col];
            acc.x += w * blo(u.x); acc.y += w * bhi(u.x);
            acc.z += w * blo(u.y); acc.w += w * bhi(u.y);
        }
        float4 rr = *(const float4*)&R[(size_t)wave * 256 + col];
        float4 bb = *(const float4*)&bias[col];
        float4 o;
        o.x = acc.x + rr.x + bb.x; o.y = acc.y + rr.y + bb.y;
        o.z = acc.z + rr.z + bb.z; o.w = acc.w + rr.w + bb.w;
        if (RELU) {
            o.x = fmaxf(o.x, 0.f); o.y = fmaxf(o.y, 0.f);
            o.z = fmaxf(o.z, 0.f); o.w = fmaxf(o.w, 0.f);
        }
        *(float4*)&hout[(size_t)wave * 256 + col] = o;
    } else {
        int col = lane * 2;
        float2 acc = {0.f, 0.f};
        for (int e = beg; e < end; e++) {
            int s = csr_src[e];
            float w = csr_ew[e];
            unsigned int u = *(const unsigned int*)&P[(size_t)s * 128 + col];
            acc.x += w * blo(u); acc.y += w * bhi(u);
        }
        float2 rr = *(const float2*)&R[(size_t)wave * 128 + col];
        float2 bb = *(const float2*)&bias[col];
        float2 o;
        o.x = acc.x + rr.x + bb.x; o.y = acc.y + rr.y + bb.y;
        if (RELU) { o.x = fmaxf(o.x, 0.f); o.y = fmaxf(o.y, 0.f); }
        *(float2*)&hout[(size_t)wave * 128 + col] = o;
    }
}

// ---------------- dual-output GEMM: out1 = A@W1 (+bias1), out2 = A@W2 ----------------
// A fp32 [M,K]; W row-major [K,NC]; out types templated (float or bf16).
template <typename T1, typename T2>
__global__ __launch_bounds__(256) void k_gemm2(const float* __restrict__ A, const float* __restrict__ W1,
                                               const float* __restrict__ W2, const float* __restrict__ bias1,
                                               T1* __restrict__ out1, T2* __restrict__ out2,
                                               int M, int K, int NC) {
    const int BM = 64, BN = 64, BK = 16;
    __shared__ float As[BM][BK + 1];
    __shared__ float B1s[BK][BN];
    __shared__ float B2s[BK][BN];
    int tid = threadIdx.x;
    int tx = tid & 15, ty = tid >> 4;
    int row0 = blockIdx.x * BM, col0 = blockIdx.y * BN;
    float acc1[4][4] = {}, acc2[4][4] = {};
    for (int kk = 0; kk < K; kk += BK) {
#pragma unroll
        for (int i = tid; i < BM * BK; i += 256) {
            int m = i >> 4, k = i & 15;
            int r = row0 + m;
            As[m][k] = (r < M) ? A[(size_t)r * K + kk + k] : 0.f;
        }
#pragma unroll
        for (int i = tid; i < BK * BN; i += 256) {
            int k = i >> 6, j = i & 63;
            B1s[k][j] = W1[(size_t)(kk + k) * NC + col0 + j];
            B2s[k][j] = W2[(size_t)(kk + k) * NC + col0 + j];
        }
        __syncthreads();
#pragma unroll
        for (int k = 0; k < BK; k++) {
            float a[4], b1[4], b2[4];
#pragma unroll
            for (int r = 0; r < 4; r++) a[r] = As[ty * 4 + r][k];
#pragma unroll
            for (int c = 0; c < 4; c++) { b1[c] = B1s[k][tx * 4 + c]; b2[c] = B2s[k][tx * 4 + c]; }
#pragma unroll
            for (int r = 0; r < 4; r++)
#pragma unroll
                for (int c = 0; c < 4; c++) {
                    acc1[r][c] += a[r] * b1[c];
                    acc2[r][c] += a[r] * b2[c];
                }
        }
        __syncthreads();
    }
#pragma unroll
    for (int r = 0; r < 4; r++) {
        int rr = row0 + ty * 4 + r;
        if (rr >= M) continue;
#pragma unroll
        for (int c = 0; c < 4; c++) {
            int cc = col0 + tx * 4 + c;
            float v1 = acc1[r][c] + (bias1 ? bias1[cc] : 0.f);
            stout(&out1[(size_t)rr * NC + cc], v1);
            stout(&out2[(size_t)rr * NC + cc], acc2[r][c]);
        }
    }
}

// ---------------- decoder: 2 pairs per wave (32 lanes x 8 cols each) ----------------
__global__ __launch_bounds__(256) void k_decoder(const ushort_t* __restrict__ Ab, const ushort_t* __restrict__ Bb,
                                                 const int* __restrict__ el,
                                                 const float* __restrict__ Wd2, const float* __restrict__ bd2,
                                                 float* __restrict__ out) {
    int wave = (blockIdx.x * 256 + threadIdx.x) >> 6;
    int lane = threadIdx.x & 63;
    int half = lane >> 5;
    int l32 = lane & 31;
    int nw = (gridDim.x * 256) >> 6;
    int col = l32 * 8;
    float4 w2a = *(const float4*)&Wd2[col];
    float4 w2b = *(const float4*)&Wd2[col + 4];
    float b2 = bd2[0];
    for (int p0 = wave * 2; p0 < N_PAIRS; p0 += nw * 2) {
        int p = p0 + half;  // N_PAIRS is even, p always valid
        int s = el[p], d = el[N_PAIRS + p];
        uint4 ua = *(const uint4*)&Ab[(size_t)s * 256 + col];
        uint4 ub = *(const uint4*)&Bb[(size_t)d * 256 + col];
        float r = 0.f, h;
        h = fmaxf(blo(ua.x) + blo(ub.x), 0.f); r += h * w2a.x;
        h = fmaxf(bhi(ua.x) + bhi(ub.x), 0.f); r += h * w2a.y;
        h = fmaxf(blo(ua.y) + blo(ub.y), 0.f); r += h * w2a.z;
        h = fmaxf(bhi(ua.y) + bhi(ub.y), 0.f); r += h * w2a.w;
        h = fmaxf(blo(ua.z) + blo(ub.z), 0.f); r += h * w2b.x;
        h = fmaxf(bhi(ua.z) + bhi(ub.z), 0.f); r += h * w2b.y;
        h = fmaxf(blo(ua.w) + blo(ub.w), 0.f); r += h * w2b.z;
        h = fmaxf(bhi(ua.w) + bhi(ub.w), 0.f); r += h * w2b.w;
#pragma unroll
        for (int off = 16; off; off >>= 1) r += __shfl_down(r, off, 32);
        if (l32 == 0) out[p] = r + b2;
    }
}

extern "C" void kernel_launch(void* const* d_in, const int* in_sizes, int n_in,
                              void* d_out, int out_size, void* d_ws, size_t ws_size,
                              hipStream_t stream) {
    const float* x   = (const float*)d_in[0];
    const int*   ei  = (const int*)d_in[1];
    const float* ew  = (const float*)d_in[2];
    const int*   el  = (const int*)d_in[3];
    const float* Wr1 = (const float*)d_in[4];
    const float* br1 = (const float*)d_in[5];
    const float* Wo1 = (const float*)d_in[6];
    const float* Wr2 = (const float*)d_in[7];
    const float* br2 = (const float*)d_in[8];
    const float* Wo2 = (const float*)d_in[9];
    const float* Wr3 = (const float*)d_in[10];
    const float* br3 = (const float*)d_in[11];
    const float* Wo3 = (const float*)d_in[12];
    const float* Wd1 = (const float*)d_in[13];
    const float* bd1 = (const float*)d_in[14];
    const float* Wd2 = (const float*)d_in[15];
    const float* bd2 = (const float*)d_in[16];
    float* out = (float*)d_out;

    char* ws = (char*)d_ws;
    size_t o = 0;
    auto alloc = [&](size_t bytes) { size_t p = o; o += (bytes + 255) & ~(size_t)255; return p; };
    int*     cnt     = (int*)(ws + alloc(N_NODES * 4));
    int*     cursor  = (int*)(ws + alloc(N_NODES * 4));
    int*     off     = (int*)(ws + alloc((N_NODES + 1) * 4));
    int*     csr_src = (int*)(ws + alloc(N_EDGES * 4));
    float*   csr_ew  = (float*)(ws + alloc(N_EDGES * 4));
    // big1: h1 [N,256] fp32, later z [N,128] fp32 (aliased; h1 dead after layer-2 GEMM)
    float*   big1    = (float*)(ws + alloc((size_t)N_NODES * 256 * 4));
    // big2: R1/R2/R3 fp32
    float*   big2    = (float*)(ws + alloc((size_t)N_NODES * 256 * 4));
    // bh1: P1/P2/P3 bf16, later A-table bf16 [N,256]
    ushort_t* bh1    = (ushort_t*)(ws + alloc((size_t)N_NODES * 256 * 2));
    // bh2: h2 fp32 [N,128], later B-table bf16 [N,256] (both 5.12 MB)
    char*    bh2raw  = ws + alloc((size_t)N_NODES * 128 * 4);
    float*   h1 = big1;
    float*   z  = big1;
    float*   h2 = (float*)bh2raw;
    ushort_t* Atab = bh1;
    ushort_t* Btab = (ushort_t*)bh2raw;

    // CSR build
    k_zero_cnt<<<(N_NODES + 255) / 256, 256, 0, stream>>>(cnt);
    k_hist<<<(N_EDGES + 255) / 256, 256, 0, stream>>>(ei, cnt);
    k_scan<<<1, 1024, 0, stream>>>(cnt, off, cursor);
    k_scatter<<<(N_EDGES + 255) / 256, 256, 0, stream>>>(ei, ew, cursor, csr_src, csr_ew);

    const int AGG_BLOCKS = (N_NODES + 3) / 4;  // 4 waves/block

    // Layer 1: P1 = x@Wr1 (bf16), R1 = x@Wo1 (fp32); h1 = relu(agg(P1)+R1+b1)
    {
        dim3 g((N_NODES + 63) / 64, 256 / 64);
        k_gemm2<ushort_t, float><<<g, 256, 0, stream>>>(x, Wr1, Wo1, nullptr, bh1, big2, N_NODES, 256, 256);
    }
    k_aggf<256, true><<<AGG_BLOCKS, 256, 0, stream>>>(bh1, big2, br1, off, csr_src, csr_ew, h1);

    // Layer 2: P2 = h1@Wr2 (bf16 [N,128]), R2 = h1@Wo2; h2 = relu(agg(P2)+R2+b2)
    {
        dim3 g((N_NODES + 63) / 64, 128 / 64);
        k_gemm2<ushort_t, float><<<g, 256, 0, stream>>>(h1, Wr2, Wo2, nullptr, bh1, big2, N_NODES, 256, 128);
    }
    k_aggf<128, true><<<AGG_BLOCKS, 256, 0, stream>>>(bh1, big2, br2, off, csr_src, csr_ew, h2);

    // Layer 3: P3 = h2@Wr3 (bf16 [N,128]), R3 = h2@Wo3; z = agg(P3)+R3+b3
    {
        dim3 g((N_NODES + 63) / 64, 128 / 64);
        k_gemm2<ushort_t, float><<<g, 256, 0, stream>>>(h2, Wr3, Wo3, nullptr, bh1, big2, N_NODES, 128, 128);
    }
    k_aggf<128, false><<<AGG_BLOCKS, 256, 0, stream>>>(bh1, big2, br3, off, csr_src, csr_ew, z);

    // Decoder tables: A = z@Wd1[:128,:] + bd1 (bf16), B = z@Wd1[128:,:] (bf16)
    {
        dim3 g((N_NODES + 63) / 64, 256 / 64);
        k_gemm2<ushort_t, ushort_t><<<g, 256, 0, stream>>>(z, Wd1, Wd1 + 128 * 256, bd1, Atab, Btab, N_NODES, 128, 256);
    }

    // Decoder
    k_decoder<<<2048, 256, 0, stream>>>(Atab, Btab, el, Wd2, bd2, out);
}

// Round 3
// 428.273 us; speedup vs baseline: 1.8251x; 1.1948x over previous
//
#include <hip/hip_runtime.h>

#define N_NODES 10000
#define N_EDGES 320000
#define N_PAIRS 1000000

typedef unsigned short ushort_t;
typedef __attribute__((ext_vector_type(8))) short short8;
typedef __attribute__((ext_vector_type(4))) float floatx4;

__device__ inline float blo(unsigned int u) { return __uint_as_float(u << 16); }
__device__ inline float bhi(unsigned int u) { return __uint_as_float(u & 0xffff0000u); }
__device__ inline ushort_t f2bf(float f) {
    unsigned int u = __float_as_uint(f);
    unsigned int r = (u + 0x7fffu + ((u >> 16) & 1u)) >> 16;
    return (ushort_t)r;
}
__device__ inline float bf2f(ushort_t b) { return __uint_as_float(((unsigned int)b) << 16); }
__device__ inline void stout(float* p, float v) { *p = v; }
__device__ inline void stout(ushort_t* p, float v) { *p = f2bf(v); }

// ---------------- CSR build ----------------
__global__ __launch_bounds__(256) void k_zero_cnt(int* cnt) {
    int i = blockIdx.x * 256 + threadIdx.x;
    if (i < N_NODES) cnt[i] = 0;
}

__global__ __launch_bounds__(256) void k_hist(const int* __restrict__ ei, int* __restrict__ cnt) {
    int e = blockIdx.x * 256 + threadIdx.x;
    if (e < N_EDGES) atomicAdd(&cnt[ei[N_EDGES + e]], 1);
}

__global__ __launch_bounds__(1024) void k_scan(const int* __restrict__ cnt,
                                               int* __restrict__ off, int* __restrict__ cursor) {
    __shared__ int part[1024];
    int t = threadIdx.x;
    int base = t * 10;
    int s = 0;
#pragma unroll
    for (int i = 0; i < 10; i++) {
        int idx = base + i;
        if (idx < N_NODES) s += cnt[idx];
    }
    part[t] = s;
    __syncthreads();
    for (int d = 1; d < 1024; d <<= 1) {
        int v = (t >= d) ? part[t - d] : 0;
        __syncthreads();
        part[t] += v;
        __syncthreads();
    }
    int run = (t == 0) ? 0 : part[t - 1];
#pragma unroll
    for (int i = 0; i < 10; i++) {
        int idx = base + i;
        if (idx < N_NODES) {
            off[idx] = run;
            cursor[idx] = run;
            run += cnt[idx];
        }
    }
    if (t == 0) off[N_NODES] = N_EDGES;
}

__global__ __launch_bounds__(256) void k_scatter(const int* __restrict__ ei, const float* __restrict__ ew,
                                                 int* __restrict__ cursor,
                                                 int* __restrict__ csr_src, float* __restrict__ csr_ew) {
    int e = blockIdx.x * 256 + threadIdx.x;
    if (e < N_EDGES) {
        int d = ei[N_EDGES + e];
        int pos = atomicAdd(&cursor[d], 1);
        csr_src[pos] = ei[e];
        csr_ew[pos] = ew[e];
    }
}

// ---------------- fused agg epilogue: hout = act(agg(P) + R + bias) ----------------
template <int C, bool RELU>
__global__ __launch_bounds__(256) void k_aggf(const ushort_t* __restrict__ P, const float* __restrict__ R,
                                              const float* __restrict__ bias,
                                              const int* __restrict__ off, const int* __restrict__ csr_src,
                                              const float* __restrict__ csr_ew,
                                              float* __restrict__ hout) {
    int wave = (blockIdx.x * 256 + threadIdx.x) >> 6;
    int lane = threadIdx.x & 63;
    if (wave >= N_NODES) return;
    int beg = off[wave], end = off[wave + 1];
    if constexpr (C == 256) {
        int col = lane * 4;
        float4 acc = {0.f, 0.f, 0.f, 0.f};
        for (int e = beg; e < end; e++) {
            int s = csr_src[e];
            float w = csr_ew[e];
            uint2 u = *(const uint2*)&P[(size_t)s * 256 + col];
            acc.x += w * blo(u.x); acc.y += w * bhi(u.x);
            acc.z += w * blo(u.y); acc.w += w * bhi(u.y);
        }
        float4 rr = *(const float4*)&R[(size_t)wave * 256 + col];
        float4 bb = *(const float4*)&bias[col];
        float4 o;
        o.x = acc.x + rr.x + bb.x; o.y = acc.y + rr.y + bb.y;
        o.z = acc.z + rr.z + bb.z; o.w = acc.w + rr.w + bb.w;
        if (RELU) {
            o.x = fmaxf(o.x, 0.f); o.y = fmaxf(o.y, 0.f);
            o.z = fmaxf(o.z, 0.f); o.w = fmaxf(o.w, 0.f);
        }
        *(float4*)&hout[(size_t)wave * 256 + col] = o;
    } else {
        int col = lane * 2;
        float2 acc = {0.f, 0.f};
        for (int e = beg; e < end; e++) {
            int s = csr_src[e];
            float w = csr_ew[e];
            unsigned int u = *(const unsigned int*)&P[(size_t)s * 128 + col];
            acc.x += w * blo(u); acc.y += w * bhi(u);
        }
        float2 rr = *(const float2*)&R[(size_t)wave * 128 + col];
        float2 bb = *(const float2*)&bias[col];
        float2 o;
        o.x = acc.x + rr.x + bb.x; o.y = acc.y + rr.y + bb.y;
        if (RELU) { o.x = fmaxf(o.x, 0.f); o.y = fmaxf(o.y, 0.f); }
        *(float2*)&hout[(size_t)wave * 128 + col] = o;
    }
}

// ---------------- MFMA dual-GEMM with bf16 hi/lo split (fp32-accurate) ----------------
// out1 = A@W1 (+bias1), out2 = A@W2. A fp32 [M,K], W fp32 [K,NC] row-major.
// 256 thr = 2x2 waves; BM=BN=64, BK=32; wave owns 2x2 16x16 tiles per output.
template <typename T1, typename T2>
__global__ __launch_bounds__(256) void k_gemm_mfma(const float* __restrict__ A, const float* __restrict__ W1,
                                                   const float* __restrict__ W2, const float* __restrict__ bias1,
                                                   T1* __restrict__ out1, T2* __restrict__ out2,
                                                   int M, int K, int NC) {
    __shared__ ushort_t As_hi[64][40], As_lo[64][40];
    __shared__ ushort_t B1_hi[64][40], B1_lo[64][40];
    __shared__ ushort_t B2_hi[64][40], B2_lo[64][40];

    int tid = threadIdx.x;
    int wid = tid >> 6, lane = tid & 63;
    int wm = wid >> 1, wn = wid & 1;
    int l15 = lane & 15, quad = lane >> 4;
    int row0 = blockIdx.x * 64, col0 = blockIdx.y * 64;

    floatx4 acc1[2][2] = {}, acc2[2][2] = {};

    for (int kk = 0; kk < K; kk += 32) {
        // --- stage A: 64 rows x 32 k, fp32 -> hi/lo bf16 ---
        {
            int row = tid >> 2, kq = (tid & 3) * 8;
            int r = row0 + row;
            union { short8 v; ushort_t u[8]; } hi, lo;
            if (r < M) {
                const float* ap = &A[(size_t)r * K + kk + kq];
                float4 f0 = *(const float4*)ap;
                float4 f1 = *(const float4*)(ap + 4);
                float f[8] = {f0.x, f0.y, f0.z, f0.w, f1.x, f1.y, f1.z, f1.w};
#pragma unroll
                for (int j = 0; j < 8; j++) {
                    ushort_t h = f2bf(f[j]);
                    hi.u[j] = h;
                    lo.u[j] = f2bf(f[j] - bf2f(h));
                }
            } else {
#pragma unroll
                for (int j = 0; j < 8; j++) { hi.u[j] = 0; lo.u[j] = 0; }
            }
            *(short8*)&As_hi[row][kq] = hi.v;
            *(short8*)&As_lo[row][kq] = lo.v;
        }
        // --- stage W1/W2: 64 cols x 32 k (transposed to [col][k]) ---
        {
            int col = tid >> 2, kg = (tid & 3) * 8;
            union { short8 v; ushort_t u[8]; } h1, l1, h2, l2;
#pragma unroll
            for (int j = 0; j < 8; j++) {
                size_t gi = (size_t)(kk + kg + j) * NC + col0 + col;
                float w1 = W1[gi], w2 = W2[gi];
                ushort_t a = f2bf(w1);
                h1.u[j] = a; l1.u[j] = f2bf(w1 - bf2f(a));
                ushort_t b = f2bf(w2);
                h2.u[j] = b; l2.u[j] = f2bf(w2 - bf2f(b));
            }
            *(short8*)&B1_hi[col][kg] = h1.v;
            *(short8*)&B1_lo[col][kg] = l1.v;
            *(short8*)&B2_hi[col][kg] = h2.v;
            *(short8*)&B2_lo[col][kg] = l2.v;
        }
        __syncthreads();

        short8 a_hi[2], a_lo[2], b1h[2], b1l[2], b2h[2], b2l[2];
#pragma unroll
        for (int t = 0; t < 2; t++) {
            int ar = wm * 32 + t * 16 + l15;
            a_hi[t] = *(const short8*)&As_hi[ar][quad * 8];
            a_lo[t] = *(const short8*)&As_lo[ar][quad * 8];
            int bc = wn * 32 + t * 16 + l15;
            b1h[t] = *(const short8*)&B1_hi[bc][quad * 8];
            b1l[t] = *(const short8*)&B1_lo[bc][quad * 8];
            b2h[t] = *(const short8*)&B2_hi[bc][quad * 8];
            b2l[t] = *(const short8*)&B2_lo[bc][quad * 8];
        }
#pragma unroll
        for (int tm = 0; tm < 2; tm++)
#pragma unroll
            for (int tn = 0; tn < 2; tn++) {
                acc1[tm][tn] = __builtin_amdgcn_mfma_f32_16x16x32_bf16(a_hi[tm], b1h[tn], acc1[tm][tn], 0, 0, 0);
                acc1[tm][tn] = __builtin_amdgcn_mfma_f32_16x16x32_bf16(a_lo[tm], b1h[tn], acc1[tm][tn], 0, 0, 0);
                acc1[tm][tn] = __builtin_amdgcn_mfma_f32_16x16x32_bf16(a_hi[tm], b1l[tn], acc1[tm][tn], 0, 0, 0);
                acc2[tm][tn] = __builtin_amdgcn_mfma_f32_16x16x32_bf16(a_hi[tm], b2h[tn], acc2[tm][tn], 0, 0, 0);
                acc2[tm][tn] = __builtin_amdgcn_mfma_f32_16x16x32_bf16(a_lo[tm], b2h[tn], acc2[tm][tn], 0, 0, 0);
                acc2[tm][tn] = __builtin_amdgcn_mfma_f32_16x16x32_bf16(a_hi[tm], b2l[tn], acc2[tm][tn], 0, 0, 0);
            }
        __syncthreads();
    }

    // epilogue: C/D layout col=lane&15, row=quad*4+reg
#pragma unroll
    for (int tm = 0; tm < 2; tm++) {
#pragma unroll
        for (int tn = 0; tn < 2; tn++) {
            int gc = col0 + wn * 32 + tn * 16 + l15;
            float bv = bias1 ? bias1[gc] : 0.f;
#pragma unroll
            for (int reg = 0; reg < 4; reg++) {
                int gr = row0 + wm * 32 + tm * 16 + quad * 4 + reg;
                if (gr >= M) continue;
                stout(&out1[(size_t)gr * NC + gc], acc1[tm][tn][reg] + bv);
                stout(&out2[(size_t)gr * NC + gc], acc2[tm][tn][reg]);
            }
        }
    }
}

// ---------------- decoder: 2 pairs per wave (32 lanes x 8 cols each) ----------------
__global__ __launch_bounds__(256) void k_decoder(const ushort_t* __restrict__ Ab, const ushort_t* __restrict__ Bb,
                                                 const int* __restrict__ el,
                                                 const float* __restrict__ Wd2, const float* __restrict__ bd2,
                                                 float* __restrict__ out) {
    int wave = (blockIdx.x * 256 + threadIdx.x) >> 6;
    int lane = threadIdx.x & 63;
    int half = lane >> 5;
    int l32 = lane & 31;
    int nw = (gridDim.x * 256) >> 6;
    int col = l32 * 8;
    float4 w2a = *(const float4*)&Wd2[col];
    float4 w2b = *(const float4*)&Wd2[col + 4];
    float b2 = bd2[0];
    for (int p0 = wave * 2; p0 < N_PAIRS; p0 += nw * 2) {
        int p = p0 + half;
        int s = el[p], d = el[N_PAIRS + p];
        uint4 ua = *(const uint4*)&Ab[(size_t)s * 256 + col];
        uint4 ub = *(const uint4*)&Bb[(size_t)d * 256 + col];
        float r = 0.f, h;
        h = fmaxf(blo(ua.x) + blo(ub.x), 0.f); r += h * w2a.x;
        h = fmaxf(bhi(ua.x) + bhi(ub.x), 0.f); r += h * w2a.y;
        h = fmaxf(blo(ua.y) + blo(ub.y), 0.f); r += h * w2a.z;
        h = fmaxf(bhi(ua.y) + bhi(ub.y), 0.f); r += h * w2a.w;
        h = fmaxf(blo(ua.z) + blo(ub.z), 0.f); r += h * w2b.x;
        h = fmaxf(bhi(ua.z) + bhi(ub.z), 0.f); r += h * w2b.y;
        h = fmaxf(blo(ua.w) + blo(ub.w), 0.f); r += h * w2b.z;
        h = fmaxf(bhi(ua.w) + bhi(ub.w), 0.f); r += h * w2b.w;
#pragma unroll
        for (int off = 16; off; off >>= 1) r += __shfl_down(r, off, 32);
        if (l32 == 0) out[p] = r + b2;
    }
}

extern "C" void kernel_launch(void* const* d_in, const int* in_sizes, int n_in,
                              void* d_out, int out_size, void* d_ws, size_t ws_size,
                              hipStream_t stream) {
    const float* x   = (const float*)d_in[0];
    const int*   ei  = (const int*)d_in[1];
    const float* ew  = (const float*)d_in[2];
    const int*   el  = (const int*)d_in[3];
    const float* Wr1 = (const float*)d_in[4];
    const float* br1 = (const float*)d_in[5];
    const float* Wo1 = (const float*)d_in[6];
    const float* Wr2 = (const float*)d_in[7];
    const float* br2 = (const float*)d_in[8];
    const float* Wo2 = (const float*)d_in[9];
    const float* Wr3 = (const float*)d_in[10];
    const float* br3 = (const float*)d_in[11];
    const float* Wo3 = (const float*)d_in[12];
    const float* Wd1 = (const float*)d_in[13];
    const float* bd1 = (const float*)d_in[14];
    const float* Wd2 = (const float*)d_in[15];
    const float* bd2 = (const float*)d_in[16];
    float* out = (float*)d_out;

    char* ws = (char*)d_ws;
    size_t o = 0;
    auto alloc = [&](size_t bytes) { size_t p = o; o += (bytes + 255) & ~(size_t)255; return p; };
    int*     cnt     = (int*)(ws + alloc(N_NODES * 4));
    int*     cursor  = (int*)(ws + alloc(N_NODES * 4));
    int*     off     = (int*)(ws + alloc((N_NODES + 1) * 4));
    int*     csr_src = (int*)(ws + alloc(N_EDGES * 4));
    float*   csr_ew  = (float*)(ws + alloc(N_EDGES * 4));
    float*   big1    = (float*)(ws + alloc((size_t)N_NODES * 256 * 4));  // h1, later z
    float*   big2    = (float*)(ws + alloc((size_t)N_NODES * 256 * 4));  // R buffers
    ushort_t* bh1    = (ushort_t*)(ws + alloc((size_t)N_NODES * 256 * 2)); // P bf16, later Atab
    char*    bh2raw  = ws + alloc((size_t)N_NODES * 128 * 4);              // h2 fp32, later Btab
    float*   h1 = big1;
    float*   z  = big1;
    float*   h2 = (float*)bh2raw;
    ushort_t* Atab = bh1;
    ushort_t* Btab = (ushort_t*)bh2raw;

    // CSR build
    k_zero_cnt<<<(N_NODES + 255) / 256, 256, 0, stream>>>(cnt);
    k_hist<<<(N_EDGES + 255) / 256, 256, 0, stream>>>(ei, cnt);
    k_scan<<<1, 1024, 0, stream>>>(cnt, off, cursor);
    k_scatter<<<(N_EDGES + 255) / 256, 256, 0, stream>>>(ei, ew, cursor, csr_src, csr_ew);

    const int AGG_BLOCKS = (N_NODES + 3) / 4;

    // Layer 1: P1 = x@Wr1 (bf16), R1 = x@Wo1 (fp32); h1 = relu(agg(P1)+R1+b1)
    {
        dim3 g((N_NODES + 63) / 64, 256 / 64);
        k_gemm_mfma<ushort_t, float><<<g, 256, 0, stream>>>(x, Wr1, Wo1, nullptr, bh1, big2, N_NODES, 256, 256);
    }
    k_aggf<256, true><<<AGG_BLOCKS, 256, 0, stream>>>(bh1, big2, br1, off, csr_src, csr_ew, h1);

    // Layer 2
    {
        dim3 g((N_NODES + 63) / 64, 128 / 64);
        k_gemm_mfma<ushort_t, float><<<g, 256, 0, stream>>>(h1, Wr2, Wo2, nullptr, bh1, big2, N_NODES, 256, 128);
    }
    k_aggf<128, true><<<AGG_BLOCKS, 256, 0, stream>>>(bh1, big2, br2, off, csr_src, csr_ew, h2);

    // Layer 3
    {
        dim3 g((N_NODES + 63) / 64, 128 / 64);
        k_gemm_mfma<ushort_t, float><<<g, 256, 0, stream>>>(h2, Wr3, Wo3, nullptr, bh1, big2, N_NODES, 128, 128);
    }
    k_aggf<128, false><<<AGG_BLOCKS, 256, 0, stream>>>(bh1, big2, br3, off, csr_src, csr_ew, z);

    // Decoder tables: A = z@Wd1[:128,:] + bd1 (bf16), B = z@Wd1[128:,:] (bf16)
    {
        dim3 g((N_NODES + 63) / 64, 256 / 64);
        k_gemm_mfma<ushort_t, ushort_t><<<g, 256, 0, stream>>>(z, Wd1, Wd1 + 128 * 256, bd1, Atab, Btab, N_NODES, 128, 256);
    }

    // Decoder
    k_decoder<<<2048, 256, 0, stream>>>(Atab, Btab, el, Wd2, bd2, out);
}

// Round 4
// 384.085 us; speedup vs baseline: 2.0350x; 1.1150x over previous
//
#include <hip/hip_runtime.h>

#define N_NODES 10000
#define N_EDGES 320000
#define N_PAIRS 1000000

typedef unsigned short ushort_t;
typedef __attribute__((ext_vector_type(8))) short short8;
typedef __attribute__((ext_vector_type(4))) float floatx4;

__device__ inline float blo(unsigned int u) { return __uint_as_float(u << 16); }
__device__ inline float bhi(unsigned int u) { return __uint_as_float(u & 0xffff0000u); }
__device__ inline ushort_t f2bf(float f) {
    unsigned int u = __float_as_uint(f);
    unsigned int r = (u + 0x7fffu + ((u >> 16) & 1u)) >> 16;
    return (ushort_t)r;
}
__device__ inline float bf2f(ushort_t b) { return __uint_as_float(((unsigned int)b) << 16); }
__device__ inline void stout(float* p, float v) { *p = v; }
__device__ inline void stout(ushort_t* p, float v) { *p = f2bf(v); }

// ---------------- CSR build ----------------
__global__ __launch_bounds__(256) void k_zero_cnt(int* cnt) {
    int i = blockIdx.x * 256 + threadIdx.x;
    if (i < N_NODES) cnt[i] = 0;
}

__global__ __launch_bounds__(256) void k_hist(const int* __restrict__ ei, int* __restrict__ cnt) {
    int e = blockIdx.x * 256 + threadIdx.x;
    if (e < N_EDGES) atomicAdd(&cnt[ei[N_EDGES + e]], 1);
}

__global__ __launch_bounds__(1024) void k_scan(const int* __restrict__ cnt,
                                               int* __restrict__ off, int* __restrict__ cursor) {
    __shared__ int part[1024];
    int t = threadIdx.x;
    int base = t * 10;
    int s = 0;
#pragma unroll
    for (int i = 0; i < 10; i++) {
        int idx = base + i;
        if (idx < N_NODES) s += cnt[idx];
    }
    part[t] = s;
    __syncthreads();
    for (int d = 1; d < 1024; d <<= 1) {
        int v = (t >= d) ? part[t - d] : 0;
        __syncthreads();
        part[t] += v;
        __syncthreads();
    }
    int run = (t == 0) ? 0 : part[t - 1];
#pragma unroll
    for (int i = 0; i < 10; i++) {
        int idx = base + i;
        if (idx < N_NODES) {
            off[idx] = run;
            cursor[idx] = run;
            run += cnt[idx];
        }
    }
    if (t == 0) off[N_NODES] = N_EDGES;
}

__global__ __launch_bounds__(256) void k_scatter(const int* __restrict__ ei, const float* __restrict__ ew,
                                                 int* __restrict__ cursor,
                                                 int* __restrict__ csr_src, float* __restrict__ csr_ew) {
    int e = blockIdx.x * 256 + threadIdx.x;
    if (e < N_EDGES) {
        int d = ei[N_EDGES + e];
        int pos = atomicAdd(&cursor[d], 1);
        csr_src[pos] = ei[e];
        csr_ew[pos] = ew[e];
    }
}

// ---------------- weight split+transpose: W[K,NC] fp32 -> Wt_hi/lo [NC,K] bf16 ----------------
__global__ __launch_bounds__(256) void k_wsplit(
    const float* Wr1, const float* Wo1, const float* Wr2, const float* Wo2,
    const float* Wr3, const float* Wo3, const float* Wd1,
    ushort_t* r1h, ushort_t* r1l, ushort_t* o1h, ushort_t* o1l,
    ushort_t* r2h, ushort_t* r2l, ushort_t* o2h, ushort_t* o2l,
    ushort_t* r3h, ushort_t* r3l, ushort_t* o3h, ushort_t* o3l,
    ushort_t* dah, ushort_t* dal, ushort_t* dbh, ushort_t* dbl) {
    const float* src; ushort_t *dh, *dl; int K, NC;
    switch (blockIdx.z) {
        case 0: src = Wr1; dh = r1h; dl = r1l; K = 256; NC = 256; break;
        case 1: src = Wo1; dh = o1h; dl = o1l; K = 256; NC = 256; break;
        case 2: src = Wr2; dh = r2h; dl = r2l; K = 256; NC = 128; break;
        case 3: src = Wo2; dh = o2h; dl = o2l; K = 256; NC = 128; break;
        case 4: src = Wr3; dh = r3h; dl = r3l; K = 128; NC = 128; break;
        case 5: src = Wo3; dh = o3h; dl = o3l; K = 128; NC = 128; break;
        case 6: src = Wd1;             dh = dah; dl = dal; K = 128; NC = 256; break;
        default: src = Wd1 + 128 * 256; dh = dbh; dl = dbl; K = 128; NC = 256; break;
    }
    int tk = blockIdx.x * 32, tn = blockIdx.y * 32;
    if (tk >= K || tn >= NC) return;
    __shared__ float tile[32][33];
    int tx = threadIdx.x & 31, ty0 = threadIdx.x >> 5;
#pragma unroll
    for (int r = 0; r < 4; r++) {
        int k = tk + ty0 + r * 8;
        tile[ty0 + r * 8][tx] = src[(size_t)k * NC + tn + tx];
    }
    __syncthreads();
#pragma unroll
    for (int r = 0; r < 4; r++) {
        int n = tn + ty0 + r * 8;
        float v = tile[tx][ty0 + r * 8];
        ushort_t h = f2bf(v);
        dh[(size_t)n * K + tk + tx] = h;
        dl[(size_t)n * K + tk + tx] = f2bf(v - bf2f(h));
    }
}

// ---------------- x split: fp32 -> hi/lo bf16 ----------------
__global__ __launch_bounds__(256) void k_xsplit(const float* __restrict__ x,
                                                ushort_t* __restrict__ xh, ushort_t* __restrict__ xl, int n4) {
    int i = blockIdx.x * 256 + threadIdx.x;
    if (i >= n4) return;
    float4 f = ((const float4*)x)[i];
    union { uint2 v; ushort_t u[4]; } H, L;
    float ff[4] = {f.x, f.y, f.z, f.w};
#pragma unroll
    for (int j = 0; j < 4; j++) {
        ushort_t h = f2bf(ff[j]);
        H.u[j] = h;
        L.u[j] = f2bf(ff[j] - bf2f(h));
    }
    ((uint2*)xh)[i] = H.v;
    ((uint2*)xl)[i] = L.v;
}

// ---------------- fused agg epilogue: h = act(agg(P) + R + bias), emitted as hi/lo bf16 ----------------
template <int C, bool RELU>
__global__ __launch_bounds__(256) void k_aggf(const ushort_t* __restrict__ P, const float* __restrict__ R,
                                              const float* __restrict__ bias,
                                              const int* __restrict__ off, const int* __restrict__ csr_src,
                                              const float* __restrict__ csr_ew,
                                              ushort_t* __restrict__ hh, ushort_t* __restrict__ hl) {
    int wave = (blockIdx.x * 256 + threadIdx.x) >> 6;
    int lane = threadIdx.x & 63;
    if (wave >= N_NODES) return;
    int beg = off[wave], end = off[wave + 1];
    if constexpr (C == 256) {
        int col = lane * 4;
        float4 acc = {0.f, 0.f, 0.f, 0.f};
        int e = beg;
        for (; e + 1 < end; e += 2) {
            int s0 = csr_src[e], s1 = csr_src[e + 1];
            float w0 = csr_ew[e], w1 = csr_ew[e + 1];
            uint2 u0 = *(const uint2*)&P[(size_t)s0 * 256 + col];
            uint2 u1 = *(const uint2*)&P[(size_t)s1 * 256 + col];
            acc.x += w0 * blo(u0.x) + w1 * blo(u1.x);
            acc.y += w0 * bhi(u0.x) + w1 * bhi(u1.x);
            acc.z += w0 * blo(u0.y) + w1 * blo(u1.y);
            acc.w += w0 * bhi(u0.y) + w1 * bhi(u1.y);
        }
        if (e < end) {
            int s0 = csr_src[e];
            float w0 = csr_ew[e];
            uint2 u0 = *(const uint2*)&P[(size_t)s0 * 256 + col];
            acc.x += w0 * blo(u0.x); acc.y += w0 * bhi(u0.x);
            acc.z += w0 * blo(u0.y); acc.w += w0 * bhi(u0.y);
        }
        float4 rr = *(const float4*)&R[(size_t)wave * 256 + col];
        float4 bb = *(const float4*)&bias[col];
        float o[4];
        o[0] = acc.x + rr.x + bb.x; o[1] = acc.y + rr.y + bb.y;
        o[2] = acc.z + rr.z + bb.z; o[3] = acc.w + rr.w + bb.w;
        if (RELU) {
#pragma unroll
            for (int j = 0; j < 4; j++) o[j] = fmaxf(o[j], 0.f);
        }
        union { uint2 v; ushort_t u[4]; } H, L;
#pragma unroll
        for (int j = 0; j < 4; j++) {
            ushort_t h = f2bf(o[j]);
            H.u[j] = h;
            L.u[j] = f2bf(o[j] - bf2f(h));
        }
        *(uint2*)&hh[(size_t)wave * 256 + col] = H.v;
        *(uint2*)&hl[(size_t)wave * 256 + col] = L.v;
    } else {
        int col = lane * 2;
        float2 acc = {0.f, 0.f};
        int e = beg;
        for (; e + 1 < end; e += 2) {
            int s0 = csr_src[e], s1 = csr_src[e + 1];
            float w0 = csr_ew[e], w1 = csr_ew[e + 1];
            unsigned int u0 = *(const unsigned int*)&P[(size_t)s0 * 128 + col];
            unsigned int u1 = *(const unsigned int*)&P[(size_t)s1 * 128 + col];
            acc.x += w0 * blo(u0) + w1 * blo(u1);
            acc.y += w0 * bhi(u0) + w1 * bhi(u1);
        }
        if (e < end) {
            int s0 = csr_src[e];
            float w0 = csr_ew[e];
            unsigned int u0 = *(const unsigned int*)&P[(size_t)s0 * 128 + col];
            acc.x += w0 * blo(u0); acc.y += w0 * bhi(u0);
        }
        float2 rr = *(const float2*)&R[(size_t)wave * 128 + col];
        float2 bb = *(const float2*)&bias[col];
        float o0 = acc.x + rr.x + bb.x, o1 = acc.y + rr.y + bb.y;
        if (RELU) { o0 = fmaxf(o0, 0.f); o1 = fmaxf(o1, 0.f); }
        union { unsigned int v; ushort_t u[2]; } H, L;
        ushort_t h0 = f2bf(o0), h1 = f2bf(o1);
        H.u[0] = h0; H.u[1] = h1;
        L.u[0] = f2bf(o0 - bf2f(h0)); L.u[1] = f2bf(o1 - bf2f(h1));
        *(unsigned int*)&hh[(size_t)wave * 128 + col] = H.v;
        *(unsigned int*)&hl[(size_t)wave * 128 + col] = L.v;
    }
}

// ---------------- pure-bf16 MFMA dual-GEMM (pre-split inputs) ----------------
// out1 = A@W1^T' (+bias1), out2 = A@W2^T'. A: hi/lo bf16 [M,K]; W: hi/lo bf16 [NC,K] (pre-transposed).
template <typename T1, typename T2>
__global__ __launch_bounds__(256) void k_gemm_bf(const ushort_t* __restrict__ Ahi, const ushort_t* __restrict__ Alo,
                                                 const ushort_t* __restrict__ W1hi, const ushort_t* __restrict__ W1lo,
                                                 const ushort_t* __restrict__ W2hi, const ushort_t* __restrict__ W2lo,
                                                 const float* __restrict__ bias1,
                                                 T1* __restrict__ out1, T2* __restrict__ out2,
                                                 int M, int K, int NC) {
    __shared__ ushort_t sAh[64][32], sAl[64][32];
    __shared__ ushort_t s1h[64][32], s1l[64][32];
    __shared__ ushort_t s2h[64][32], s2l[64][32];

    int tid = threadIdx.x;
    int lane = tid & 63, wid = tid >> 6;
    int wm = wid >> 1, wn = wid & 1;
    int l15 = lane & 15, quad = lane >> 4;
    int row0 = blockIdx.x * 64, col0 = blockIdx.y * 64;

    int srow = tid >> 2, schunk = (tid & 3) * 8;
    int arow = row0 + srow; if (arow > M - 1) arow = M - 1;
    const ushort_t* gAh = Ahi + (size_t)arow * K + schunk;
    const ushort_t* gAl = Alo + (size_t)arow * K + schunk;
    int wrow = col0 + srow;
    const ushort_t* g1h = W1hi + (size_t)wrow * K + schunk;
    const ushort_t* g1l = W1lo + (size_t)wrow * K + schunk;
    const ushort_t* g2h = W2hi + (size_t)wrow * K + schunk;
    const ushort_t* g2l = W2lo + (size_t)wrow * K + schunk;
    ushort_t* lAh = &sAh[srow][schunk];
    ushort_t* lAl = &sAl[srow][schunk];
    ushort_t* l1h = &s1h[srow][schunk];
    ushort_t* l1l = &s1l[srow][schunk];
    ushort_t* l2h = &s2h[srow][schunk];
    ushort_t* l2l = &s2l[srow][schunk];

    floatx4 acc1[2][2] = {}, acc2[2][2] = {};

    for (int kk = 0; kk < K; kk += 32) {
        *(short8*)lAh = *(const short8*)(gAh + kk);
        *(short8*)lAl = *(const short8*)(gAl + kk);
        *(short8*)l1h = *(const short8*)(g1h + kk);
        *(short8*)l1l = *(const short8*)(g1l + kk);
        *(short8*)l2h = *(const short8*)(g2h + kk);
        *(short8*)l2l = *(const short8*)(g2l + kk);
        __syncthreads();

        short8 ah[2], al[2], b1h[2], b1l[2], b2h[2], b2l[2];
#pragma unroll
        for (int t = 0; t < 2; t++) {
            int ar = wm * 32 + t * 16 + l15;
            ah[t] = *(const short8*)&sAh[ar][quad * 8];
            al[t] = *(const short8*)&sAl[ar][quad * 8];
            int bc = wn * 32 + t * 16 + l15;
            b1h[t] = *(const short8*)&s1h[bc][quad * 8];
            b1l[t] = *(const short8*)&s1l[bc][quad * 8];
            b2h[t] = *(const short8*)&s2h[bc][quad * 8];
            b2l[t] = *(const short8*)&s2l[bc][quad * 8];
        }
#pragma unroll
        for (int tm = 0; tm < 2; tm++)
#pragma unroll
            for (int tn = 0; tn < 2; tn++) {
                acc1[tm][tn] = __builtin_amdgcn_mfma_f32_16x16x32_bf16(ah[tm], b1h[tn], acc1[tm][tn], 0, 0, 0);
                acc1[tm][tn] = __builtin_amdgcn_mfma_f32_16x16x32_bf16(al[tm], b1h[tn], acc1[tm][tn], 0, 0, 0);
                acc1[tm][tn] = __builtin_amdgcn_mfma_f32_16x16x32_bf16(ah[tm], b1l[tn], acc1[tm][tn], 0, 0, 0);
                acc2[tm][tn] = __builtin_amdgcn_mfma_f32_16x16x32_bf16(ah[tm], b2h[tn], acc2[tm][tn], 0, 0, 0);
                acc2[tm][tn] = __builtin_amdgcn_mfma_f32_16x16x32_bf16(al[tm], b2h[tn], acc2[tm][tn], 0, 0, 0);
                acc2[tm][tn] = __builtin_amdgcn_mfma_f32_16x16x32_bf16(ah[tm], b2l[tn], acc2[tm][tn], 0, 0, 0);
            }
        __syncthreads();
    }

    // C/D layout: col = lane&15, row = quad*4 + reg
#pragma unroll
    for (int tm = 0; tm < 2; tm++) {
#pragma unroll
        for (int tn = 0; tn < 2; tn++) {
            int gc = col0 + wn * 32 + tn * 16 + l15;
            float bv = bias1 ? bias1[gc] : 0.f;
#pragma unroll
            for (int reg = 0; reg < 4; reg++) {
                int gr = row0 + wm * 32 + tm * 16 + quad * 4 + reg;
                if (gr >= M) continue;
                stout(&out1[(size_t)gr * NC + gc], acc1[tm][tn][reg] + bv);
                stout(&out2[(size_t)gr * NC + gc], acc2[tm][tn][reg]);
            }
        }
    }
}

// ---------------- decoder: 2 pairs per 32-lane half, 4 gathers in flight ----------------
__device__ inline float dot8relu(uint4 ua, uint4 ub, float4 w2a, float4 w2b) {
    float r = 0.f, h;
    h = fmaxf(blo(ua.x) + blo(ub.x), 0.f); r += h * w2a.x;
    h = fmaxf(bhi(ua.x) + bhi(ub.x), 0.f); r += h * w2a.y;
    h = fmaxf(blo(ua.y) + blo(ub.y), 0.f); r += h * w2a.z;
    h = fmaxf(bhi(ua.y) + bhi(ub.y), 0.f); r += h * w2a.w;
    h = fmaxf(blo(ua.z) + blo(ub.z), 0.f); r += h * w2b.x;
    h = fmaxf(bhi(ua.z) + bhi(ub.z), 0.f); r += h * w2b.y;
    h = fmaxf(blo(ua.w) + blo(ub.w), 0.f); r += h * w2b.z;
    h = fmaxf(bhi(ua.w) + bhi(ub.w), 0.f); r += h * w2b.w;
    return r;
}

__global__ __launch_bounds__(256) void k_decoder(const ushort_t* __restrict__ Ab, const ushort_t* __restrict__ Bb,
                                                 const int* __restrict__ el,
                                                 const float* __restrict__ Wd2, const float* __restrict__ bd2,
                                                 float* __restrict__ out) {
    int wave = (blockIdx.x * 256 + threadIdx.x) >> 6;
    int lane = threadIdx.x & 63;
    int half = lane >> 5;
    int l32 = lane & 31;
    int nw = (gridDim.x * 256) >> 6;
    int col = l32 * 8;
    float4 w2a = *(const float4*)&Wd2[col];
    float4 w2b = *(const float4*)&Wd2[col + 4];
    float b2 = bd2[0];
    for (int p0 = wave * 4; p0 < N_PAIRS; p0 += nw * 4) {
        int p = p0 + half * 2;  // pairs p, p+1 (N_PAIRS % 4 == 0)
        int2 ss = *(const int2*)&el[p];
        int2 dd = *(const int2*)&el[N_PAIRS + p];
        uint4 ua0 = *(const uint4*)&Ab[(size_t)ss.x * 256 + col];
        uint4 ub0 = *(const uint4*)&Bb[(size_t)dd.x * 256 + col];
        uint4 ua1 = *(const uint4*)&Ab[(size_t)ss.y * 256 + col];
        uint4 ub1 = *(const uint4*)&Bb[(size_t)dd.y * 256 + col];
        float r0 = dot8relu(ua0, ub0, w2a, w2b);
        float r1 = dot8relu(ua1, ub1, w2a, w2b);
#pragma unroll
        for (int off = 16; off; off >>= 1) {
            r0 += __shfl_down(r0, off, 32);
            r1 += __shfl_down(r1, off, 32);
        }
        if (l32 == 0) {
            float2 o = {r0 + b2, r1 + b2};
            *(float2*)&out[p] = o;
        }
    }
}

extern "C" void kernel_launch(void* const* d_in, const int* in_sizes, int n_in,
                              void* d_out, int out_size, void* d_ws, size_t ws_size,
                              hipStream_t stream) {
    const float* x   = (const float*)d_in[0];
    const int*   ei  = (const int*)d_in[1];
    const float* ew  = (const float*)d_in[2];
    const int*   el  = (const int*)d_in[3];
    const float* Wr1 = (const float*)d_in[4];
    const float* br1 = (const float*)d_in[5];
    const float* Wo1 = (const float*)d_in[6];
    const float* Wr2 = (const float*)d_in[7];
    const float* br2 = (const float*)d_in[8];
    const float* Wo2 = (const float*)d_in[9];
    const float* Wr3 = (const float*)d_in[10];
    const float* br3 = (const float*)d_in[11];
    const float* Wo3 = (const float*)d_in[12];
    const float* Wd1 = (const float*)d_in[13];
    const float* bd1 = (const float*)d_in[14];
    const float* Wd2 = (const float*)d_in[15];
    const float* bd2 = (const float*)d_in[16];
    float* out = (float*)d_out;

    char* ws = (char*)d_ws;
    size_t o = 0;
    auto alloc = [&](size_t bytes) { size_t p = o; o += (bytes + 255) & ~(size_t)255; return (void*)(ws + p); };
    int*     cnt     = (int*)alloc(N_NODES * 4);
    int*     cursor  = (int*)alloc(N_NODES * 4);
    int*     off     = (int*)alloc((N_NODES + 1) * 4);
    int*     csr_src = (int*)alloc(N_EDGES * 4);
    float*   csr_ew  = (float*)alloc(N_EDGES * 4);
    // activation hi/lo buffers (x -> h1 -> h2 -> z, all aliased)
    ushort_t* ash = (ushort_t*)alloc((size_t)N_NODES * 256 * 2);
    ushort_t* asl = (ushort_t*)alloc((size_t)N_NODES * 256 * 2);
    // GEMM outputs: P bf16 [N,256] (later Atab), R fp32 [N,256] (later Btab)
    ushort_t* Pb  = (ushort_t*)alloc((size_t)N_NODES * 256 * 2);
    float*    Rb  = (float*)alloc((size_t)N_NODES * 256 * 4);
    // pre-split transposed weights
    ushort_t* r1h = (ushort_t*)alloc(256 * 256 * 2); ushort_t* r1l = (ushort_t*)alloc(256 * 256 * 2);
    ushort_t* o1h = (ushort_t*)alloc(256 * 256 * 2); ushort_t* o1l = (ushort_t*)alloc(256 * 256 * 2);
    ushort_t* r2h = (ushort_t*)alloc(128 * 256 * 2); ushort_t* r2l = (ushort_t*)alloc(128 * 256 * 2);
    ushort_t* o2h = (ushort_t*)alloc(128 * 256 * 2); ushort_t* o2l = (ushort_t*)alloc(128 * 256 * 2);
    ushort_t* r3h = (ushort_t*)alloc(128 * 128 * 2); ushort_t* r3l = (ushort_t*)alloc(128 * 128 * 2);
    ushort_t* o3h = (ushort_t*)alloc(128 * 128 * 2); ushort_t* o3l = (ushort_t*)alloc(128 * 128 * 2);
    ushort_t* dah = (ushort_t*)alloc(256 * 128 * 2); ushort_t* dal = (ushort_t*)alloc(256 * 128 * 2);
    ushort_t* dbh = (ushort_t*)alloc(256 * 128 * 2); ushort_t* dbl = (ushort_t*)alloc(256 * 128 * 2);
    ushort_t* Atab = Pb;
    ushort_t* Btab = (ushort_t*)Rb;

    // pre-split weights + x
    {
        dim3 g(8, 8, 8);
        k_wsplit<<<g, 256, 0, stream>>>(Wr1, Wo1, Wr2, Wo2, Wr3, Wo3, Wd1,
                                        r1h, r1l, o1h, o1l, r2h, r2l, o2h, o2l,
                                        r3h, r3l, o3h, o3l, dah, dal, dbh, dbl);
    }
    k_xsplit<<<(N_NODES * 256 / 4 + 255) / 256, 256, 0, stream>>>(x, ash, asl, N_NODES * 256 / 4);

    // CSR build
    k_zero_cnt<<<(N_NODES + 255) / 256, 256, 0, stream>>>(cnt);
    k_hist<<<(N_EDGES + 255) / 256, 256, 0, stream>>>(ei, cnt);
    k_scan<<<1, 1024, 0, stream>>>(cnt, off, cursor);
    k_scatter<<<(N_EDGES + 255) / 256, 256, 0, stream>>>(ei, ew, cursor, csr_src, csr_ew);

    const int AGG_BLOCKS = (N_NODES + 3) / 4;
    const int GX = (N_NODES + 63) / 64;

    // Layer 1: P1 = x@Wr1 (bf16), R1 = x@Wo1 (fp32); h1 = relu(agg(P1)+R1+b1) -> hi/lo
    k_gemm_bf<ushort_t, float><<<dim3(GX, 4), 256, 0, stream>>>(ash, asl, r1h, r1l, o1h, o1l, nullptr,
                                                                Pb, Rb, N_NODES, 256, 256);
    k_aggf<256, true><<<AGG_BLOCKS, 256, 0, stream>>>(Pb, Rb, br1, off, csr_src, csr_ew, ash, asl);

    // Layer 2 (NC=128)
    k_gemm_bf<ushort_t, float><<<dim3(GX, 2), 256, 0, stream>>>(ash, asl, r2h, r2l, o2h, o2l, nullptr,
                                                                Pb, Rb, N_NODES, 256, 128);
    k_aggf<128, true><<<AGG_BLOCKS, 256, 0, stream>>>(Pb, Rb, br2, off, csr_src, csr_ew, ash, asl);

    // Layer 3 (K=128, NC=128, no relu)
    k_gemm_bf<ushort_t, float><<<dim3(GX, 2), 256, 0, stream>>>(ash, asl, r3h, r3l, o3h, o3l, nullptr,
                                                                Pb, Rb, N_NODES, 128, 128);
    k_aggf<128, false><<<AGG_BLOCKS, 256, 0, stream>>>(Pb, Rb, br3, off, csr_src, csr_ew, ash, asl);

    // Decoder tables: Atab = z@Wd1_top + bd1, Btab = z@Wd1_bot (both bf16)
    k_gemm_bf<ushort_t, ushort_t><<<dim3(GX, 4), 256, 0, stream>>>(ash, asl, dah, dal, dbh, dbl, bd1,
                                                                   Atab, Btab, N_NODES, 128, 256);

    // Decoder
    k_decoder<<<2048, 256, 0, stream>>>(Atab, Btab, el, Wd2, bd2, out);
}